// Round 1
// baseline (2444.397 us; speedup 1.0000x reference)
//
#include <hip/hip_runtime.h>
#include <hip/hip_bf16.h>

typedef __bf16  bf16x8 __attribute__((ext_vector_type(8)));
typedef float   f32x4  __attribute__((ext_vector_type(4)));

__device__ __constant__ int EDGE_A[19] = {1,8,9,1,11,12,1,2,3,2,1,5,6,5,0,0,0,14,15};
__device__ __constant__ int EDGE_B[19] = {8,9,10,11,12,13,2,3,4,16,5,6,7,17,1,14,15,16,17};

#define SACT  64.0f            // activation & weight quant scale
#define SINV  (1.0f / 4096.0f) // 1/(Sw*Sa)
#define SREQ  0.015625f        // SINV*SACT = 1/64 (requant multiplier)

// compile-time tap byte offset: tap t in row-major [*,SIN] image, GR bytes/px
__device__ constexpr int ctoff(int t, int sin, int gr) {
    int tt = t > 24 ? 24 : t;
    return ((tt / 5) * sin + (tt % 5)) * gr;
}

__device__ __forceinline__ unsigned short f2bf(float f) {
    unsigned int x = __float_as_uint(f);
    x += 0x7FFFu + ((x >> 16) & 1u);
    return (unsigned short)(x >> 16);
}
__device__ __forceinline__ unsigned int pack2(float a, float b) {
    __hip_bfloat162 t = __float22bfloat162_rn(make_float2(a, b));
    unsigned int r; __builtin_memcpy(&r, &t, 4); return r;
}
__device__ __forceinline__ unsigned char f2fp8(float v) {
    int r = __builtin_amdgcn_cvt_pk_fp8_f32(v, 0.f, 0, false);
    return (unsigned char)(r & 0xff);
}
__device__ __forceinline__ unsigned int pk4fp8(float a, float b, float c, float d) {
    int v = __builtin_amdgcn_cvt_pk_fp8_f32(a, b, 0, false);
    v = __builtin_amdgcn_cvt_pk_fp8_f32(c, d, v, true);
    return (unsigned int)v;
}
// quantized epilogue: relu(acc*s + bias_prescaled) -> fp8x4
__device__ __forceinline__ unsigned int quant4(f32x4 a, float4 b, float s, bool oob) {
    float v0 = fmaxf(fmaf(a[0], s, b.x), 0.f);
    float v1 = fmaxf(fmaf(a[1], s, b.y), 0.f);
    float v2 = fmaxf(fmaf(a[2], s, b.z), 0.f);
    float v3 = fmaxf(fmaf(a[3], s, b.w), 0.f);
    unsigned int v = pk4fp8(v0, v1, v2, v3);
    return oob ? 0u : v;
}

__device__ __forceinline__ void store_relu4(unsigned char* dst, f32x4 a, float4 b, bool oob) {
    unsigned int lo = pack2(fmaxf(a[0] + b.x, 0.f), fmaxf(a[1] + b.y, 0.f));
    unsigned int hi = pack2(fmaxf(a[2] + b.z, 0.f), fmaxf(a[3] + b.w, 0.f));
    uint2 v; v.x = oob ? 0u : lo; v.y = oob ? 0u : hi;
    *(uint2*)dst = v;
}

// ---------------------------------------------------------------------------
// Weight pre-pass, ws BYTE layout (UNCHANGED):
//   W5 bf16 @0     : 8nt x 16 x 32 shorts            ( 8192 B)
//   W0 bf16 @8192  : 4c x 16 x 32 shorts             ( 4096 B)
//   W1 fp8  @12288 : 13tp x 16n x 32k, x64           ( 6656 B)
//   W2 fp8  @18944 : 13tp x 2nt x 16 x 32, x64       (13312 B)
//   W3 fp8  @32256 : 25tap x 2nt x 16 x 32 (k=ic)    (25600 B)
//   W4 fp8  @57856 : 25tap x 2nt x 16 x 32 (k=ic)    (25600 B)
// total 83456 B
// ---------------------------------------------------------------------------
extern "C" __global__ void __launch_bounds__(256)
reorder_weights(const float* __restrict__ w0, const float* __restrict__ w1,
                const float* __restrict__ w2, const float* __restrict__ w3,
                const float* __restrict__ w4, const float* __restrict__ w5,
                unsigned char* __restrict__ ws)
{
    int idx = blockIdx.x * 256 + threadIdx.x;
    unsigned short* wsS = (unsigned short*)ws;
    if (idx < 4096) {                       // W5 bf16
        int k = idx & 31, oc = idx >> 5;
        wsS[idx] = f2bf(w5[oc * 32 + k]);
    } else if (idx < 6144) {                // W0 bf16
        int j = idx - 4096;
        int k = j & 31, n = (j >> 5) & 15, c = j >> 9;
        int t = c * 8 + (k >> 2), ic = k & 3;
        float v = (t < 25) ? w0[(n * 4 + ic) * 25 + t] : 0.f;
        wsS[idx] = f2bf(v);
    }
    if (idx < 6656) {                       // W1 fp8
        int k = idx & 31, n = (idx >> 5) & 15, tp = idx >> 9;
        int t = 2 * tp + (k >> 4), ic = k & 15;
        float v = (t < 25) ? w1[(n * 16 + ic) * 25 + t] * SACT : 0.f;
        ws[12288 + idx] = f2fp8(v);
    } else if (idx < 19968) {               // W2 fp8
        int j = idx - 6656;
        int k = j & 31, n = (j >> 5) & 15, nt = (j >> 9) & 1, tp = j >> 10;
        int t = 2 * tp + (k >> 4), ic = k & 15, oc = nt * 16 + n;
        float v = (t < 25) ? w2[(oc * 16 + ic) * 25 + t] * SACT : 0.f;
        ws[18944 + j] = f2fp8(v);
    } else if (idx < 45568) {               // W3 fp8
        int j = idx - 19968;
        int k = j & 31, n = (j >> 5) & 15, nt = (j >> 9) & 1, tap = j >> 10;
        ws[32256 + j] = f2fp8(w3[((nt * 16 + n) * 32 + k) * 25 + tap] * SACT);
    } else if (idx < 71168) {               // W4 fp8
        int j = idx - 45568;
        int k = j & 31, n = (j >> 5) & 15, nt = (j >> 9) & 1, tap = j >> 10;
        ws[57856 + j] = f2fp8(w4[((nt * 16 + n) * 32 + k) * 25 + tap] * SACT);
    }
}

// ---------------------------------------------------------------------------
// conv0 (4->16) bf16 MFMA on an 18-row slab; OUTPUT fp8 x64 -> s0 16B/px rows.
// No swizzle: 4B stores at stride 16B are <=2-way.
// ---------------------------------------------------------------------------
__device__ __forceinline__ void conv0_slab(
    const unsigned short* __restrict__ s_in, unsigned char* __restrict__ s0,
    const unsigned char* __restrict__ wB, const float* __restrict__ b0,
    int yoff, int oy, int ox, int wave, int lane)
{
    const int nl = lane & 15, quad = lane >> 4;
    const unsigned short* w0p = (const unsigned short*)(wB + 8192);
    bf16x8 wf[4];
#pragma unroll
    for (int c = 0; c < 4; ++c)
        wf[c] = *(const bf16x8*)(w0p + c * 512 + nl * 32 + quad * 8);
    float4 bb = *(const float4*)(b0 + quad * 4);
    float4 bbs = make_float4(bb.x * SACT, bb.y * SACT, bb.z * SACT, bb.w * SACT);

    // per-c tap byte offsets (depend only on quad) hoisted out of the i-loop
    int coff0[4], coff1[4];
#pragma unroll
    for (int c = 0; c < 4; ++c) {
        int t0 = c * 8 + quad * 2, t1 = t0 + 1;
        if (t0 > 24) t0 = 24;
        if (t1 > 24) t1 = 24;
        coff0[c] = ((t0 / 5) * 36 + (t0 % 5)) * 8;
        coff1[c] = ((t1 / 5) * 36 + (t1 % 5)) * 8;
    }
    const unsigned char* sB = (const unsigned char*)s_in;

#pragma unroll 1
    for (int i = 0; i < 9; ++i) {
        int mt = wave + 4 * i;                 // 36 mtiles = 576 px (18r x 32)
        int p = mt * 16 + nl;
        int y = p >> 5, x = p & 31;
        int abase = (y * 36 + x) * 8;
        f32x4 acc = (f32x4)0.f;
#pragma unroll
        for (int c = 0; c < 4; ++c) {
            uint2 lo = *(const uint2*)(sB + abase + coff0[c]);
            uint2 hi = *(const uint2*)(sB + abase + coff1[c]);
            bf16x8 a;
            ((uint2*)&a)[0] = lo; ((uint2*)&a)[1] = hi;
            acc = __builtin_amdgcn_mfma_f32_16x16x32_bf16(wf[c], a, acc, 0, 0, 0);
        }
        bool oob = ((unsigned)(oy - 8 + y + yoff) >= 128u) || ((unsigned)(ox - 8 + x) >= 128u);
        *(unsigned int*)(s0 + p * 16 + quad * 4) = quant4(acc, bbs, SACT, oob);
    }
}

// ---------------------------------------------------------------------------
// conv1 half-slab, FP8: in s0 (18r x 32, 16B/px), out s1 (28x28, 16B/px).
// Paired-tap (K=32 = 2 taps x 16ch). Tap offsets: cndmask between two
// compile-time constants (full tap unroll), hoisted out of the i-loop.
// ---------------------------------------------------------------------------
__device__ __forceinline__ void conv1_fp8(
    const unsigned char* __restrict__ s0, unsigned char* __restrict__ s1,
    const unsigned char* __restrict__ wB, const float* __restrict__ b1,
    int POFF, int gy0, int gx0, int wave, int lane)
{
    const int nl = lane & 15, quad = lane >> 4;
    const int h = quad >> 1, g8 = (quad & 1) * 8;

    int abase[7];
#pragma unroll
    for (int i = 0; i < 7; ++i) {
        int p = (wave + 4 * i) * 16 + nl;
        if (p > 391) p = 391;
        int y = p / 28, x = p - y * 28;
        abase[i] = (y * 32 + x) * 16 + g8;
    }
    f32x4 acc[7];
#pragma unroll
    for (int i = 0; i < 7; ++i) acc[i] = (f32x4)0.f;

    const unsigned char* wp = wB + 12288 + nl * 32 + quad * 8;

#pragma unroll
    for (int tp = 0; tp < 13; ++tp) {
        long wl = *(const long*)(wp + tp * 512);
        int to = h ? ctoff(2 * tp + 1, 32, 16) : ctoff(2 * tp, 32, 16);
#pragma unroll
        for (int i = 0; i < 7; ++i)
            if (wave + 4 * i < 25) {
                long a = *(const long*)(s0 + abase[i] + to);
                acc[i] = __builtin_amdgcn_mfma_f32_16x16x32_fp8_fp8(wl, a, acc[i], 0, 0, 0);
            }
    }

    float4 bb = *(const float4*)(b1 + quad * 4);
    float4 bbs = make_float4(bb.x * SACT, bb.y * SACT, bb.z * SACT, bb.w * SACT);
#pragma unroll
    for (int i = 0; i < 7; ++i) {
        int p = (wave + 4 * i) * 16 + nl;
        if (p < 392) {
            int pg = p + POFF;
            int y = pg / 28, x = pg - y * 28;
            bool oob = ((unsigned)(gy0 + y) >= 128u) || ((unsigned)(gx0 + x) >= 128u);
            *(unsigned int*)(s1 + pg * 16 + quad * 4) = quant4(acc[i], bbs, SREQ, oob);
        }
    }
}

// ---------------------------------------------------------------------------
// conv2: fp8 paired-tap (CIN=16), NT=2, two m-passes (I0/NI) to bound regs.
// in s1 [784 px][16B], out s2 = 2 planes of [576 px][16B] (plane stride 9216).
// ---------------------------------------------------------------------------
template<int I0, int NI>
__device__ __forceinline__ void conv2_fp8(
    const unsigned char* __restrict__ s1, unsigned char* __restrict__ s2,
    const unsigned char* __restrict__ wA, const float* __restrict__ b2,
    int gy0, int gx0, int wave, int lane)
{
    const int nl = lane & 15, quad = lane >> 4;
    const int h = quad >> 1, g8 = (quad & 1) * 8;

    int abase[NI];
#pragma unroll
    for (int i = 0; i < NI; ++i) {
        int p = (wave + 4 * (I0 + i)) * 16 + nl;
        int y = p / 24, x = p - y * 24;
        abase[i] = (y * 28 + x) * 16 + g8;
    }
    f32x4 acc[NI][2];
#pragma unroll
    for (int i = 0; i < NI; ++i) { acc[i][0] = (f32x4)0.f; acc[i][1] = (f32x4)0.f; }

    const unsigned char* wp = wA + nl * 32 + quad * 8;

#pragma unroll
    for (int tp = 0; tp < 13; ++tp) {
        long wl0 = *(const long*)(wp + (tp * 2 + 0) * 512);
        long wl1 = *(const long*)(wp + (tp * 2 + 1) * 512);
        int to = h ? ctoff(2 * tp + 1, 28, 16) : ctoff(2 * tp, 28, 16);
#pragma unroll
        for (int i = 0; i < NI; ++i) {
            long a = *(const long*)(s1 + abase[i] + to);
            acc[i][0] = __builtin_amdgcn_mfma_f32_16x16x32_fp8_fp8(wl0, a, acc[i][0], 0, 0, 0);
            acc[i][1] = __builtin_amdgcn_mfma_f32_16x16x32_fp8_fp8(wl1, a, acc[i][1], 0, 0, 0);
        }
    }

#pragma unroll
    for (int i = 0; i < NI; ++i) {
        int p = (wave + 4 * (I0 + i)) * 16 + nl;
        int y = p / 24, x = p - y * 24;
        bool oob = ((unsigned)(gy0 + y) >= 128u) || ((unsigned)(gx0 + x) >= 128u);
#pragma unroll
        for (int nt = 0; nt < 2; ++nt) {
            float4 bb = *(const float4*)(b2 + nt * 16 + quad * 4);
            float4 bbs = make_float4(bb.x * SACT, bb.y * SACT, bb.z * SACT, bb.w * SACT);
            *(unsigned int*)(s2 + nt * 9216 + p * 16 + quad * 4) =
                quant4(acc[i][nt], bbs, SREQ, oob);
        }
    }
}

// ---------------------------------------------------------------------------
// conv3/conv4: fp8 25-tap (CIN=32, K=32=ic), NT=2, chunk CH.
// in: 2 planes of 16B/px (stride PLANE_IN); tap t wave-uniform -> SALU toff.
// FP8OUT: fp8 to 2 planes (stride PLANE_OUT); else bf16 to 4 planes.
// ---------------------------------------------------------------------------
template<int SIN, int SOUT, int MAXM, bool GUARD, bool FP8OUT, int CH,
         int PLANE_IN, int PLANE_OUT>
__device__ __forceinline__ void conv_c32_fp8(
    const unsigned char* __restrict__ sinB, unsigned char* __restrict__ soutB,
    const unsigned char* __restrict__ wA, const float* __restrict__ bias,
    int gy0, int gx0, int wave, int lane)
{
    constexpr int NM = (SOUT * SOUT) / 16;
    const int nl = lane & 15, quad = lane >> 4;

    int abase[MAXM];
#pragma unroll
    for (int i = 0; i < MAXM; ++i) {
        int p = (wave + 4 * i) * 16 + nl;
        if (GUARD && p > SOUT * SOUT - 1) p = SOUT * SOUT - 1;
        int y = p / SOUT, x = p - y * SOUT;
        abase[i] = (y * SIN + x) * 16 + (quad & 1) * 8 + (quad >> 1) * PLANE_IN;
    }
    f32x4 acc[MAXM][2];
#pragma unroll
    for (int i = 0; i < MAXM; ++i) { acc[i][0] = (f32x4)0.f; acc[i][1] = (f32x4)0.f; }

    const unsigned char* wp = wA + nl * 32 + quad * 8;

#pragma unroll 1
    for (int c0 = 0; c0 < 25; c0 += CH) {
        long wl[CH][2];
#pragma unroll
        for (int tp = 0; tp < CH; ++tp)
            if (c0 + tp < 25) {
                wl[tp][0] = *(const long*)(wp + ((c0 + tp) * 2 + 0) * 512);
                wl[tp][1] = *(const long*)(wp + ((c0 + tp) * 2 + 1) * 512);
            }
#pragma unroll
        for (int tp = 0; tp < CH; ++tp) {
            if (c0 + tp < 25) {
                int t = c0 + tp;                       // wave-uniform -> SALU
                int dy = t / 5, dx = t - 5 * dy;
                int to = (dy * SIN + dx) * 16;
#pragma unroll
                for (int i = 0; i < MAXM; ++i)
                    if (!GUARD || wave + 4 * i < NM) {
                        long a = *(const long*)(sinB + abase[i] + to);
                        acc[i][0] = __builtin_amdgcn_mfma_f32_16x16x32_fp8_fp8(wl[tp][0], a, acc[i][0], 0, 0, 0);
                        acc[i][1] = __builtin_amdgcn_mfma_f32_16x16x32_fp8_fp8(wl[tp][1], a, acc[i][1], 0, 0, 0);
                    }
            }
        }
    }

#pragma unroll
    for (int i = 0; i < MAXM; ++i) {
        int p = (wave + 4 * i) * 16 + nl;
        if (!GUARD || p < SOUT * SOUT) {
            int y = p / SOUT, x = p - y * SOUT;
            bool oob = ((unsigned)(gy0 + y) >= 128u) || ((unsigned)(gx0 + x) >= 128u);
#pragma unroll
            for (int nt = 0; nt < 2; ++nt) {
                float4 bb = *(const float4*)(bias + nt * 16 + quad * 4);
                if (FP8OUT) {
                    float4 bbs = make_float4(bb.x * SACT, bb.y * SACT, bb.z * SACT, bb.w * SACT);
                    *(unsigned int*)(soutB + nt * PLANE_OUT + p * 16 + quad * 4) =
                        quant4(acc[i][nt], bbs, SREQ, oob);
                } else {
                    f32x4 s;
                    s[0] = acc[i][nt][0] * SINV; s[1] = acc[i][nt][1] * SINV;
                    s[2] = acc[i][nt][2] * SINV; s[3] = acc[i][nt][3] * SINV;
                    store_relu4(soutB + (2 * nt + (quad >> 1)) * PLANE_OUT
                                      + p * 16 + (quad & 1) * 8, s, bb, oob);
                }
            }
        }
    }
}

// ---------------------------------------------------------------------------
// Fused pipeline: 256 threads = one 16x16 output tile. LDS 31232 B:
//   s1 @0 12544 | s3 @0 2x6400 | sin @12800 6336 | s0 @19136 9216
//   s2 @12800 2x9216 | s4 @12800 4x4096   (ping-pong, liveness-checked)
// ---------------------------------------------------------------------------
extern "C" __global__ void __launch_bounds__(256, 3)
gnn_paf_mfma(const float* __restrict__ cnn, const unsigned char* __restrict__ wB,
             const float* __restrict__ b0, const float* __restrict__ b1,
             const float* __restrict__ b2, const float* __restrict__ b3,
             const float* __restrict__ b4, const float* __restrict__ b5,
             const float* __restrict__ w6, const float* __restrict__ b6,
             float* __restrict__ out)
{
    __shared__ __align__(64) unsigned char smem[31232];
    unsigned char*  const s1   = smem;                             // 12544
    unsigned char*  const s3   = smem;                             // 2 x 6400
    unsigned short* const sin_ = (unsigned short*)(smem + 12800);  // 6336
    unsigned char*  const s0   = smem + 19136;                     // 9216
    unsigned char*  const s2   = smem + 12800;                     // 2 x 9216
    unsigned char*  const s4   = smem + 12800;                     // 4 x 4096

    const int tid  = threadIdx.x;
    const int lane = tid & 63, wave = tid >> 6;       // 4 waves
    const int tile = blockIdx.x, img = blockIdx.y;
    const int oy = (tile >> 3) * 16, ox = (tile & 7) * 16;
    const int n = img / 19, g = img - n * 19;
    const int ch0 = EDGE_A[g], ch1 = EDGE_B[g], ch2 = 19 + 2 * g, ch3 = 20 + 2 * g;
    const int nl = lane & 15, quad = lane >> 4;
    const long long nb = (long long)n * 57 * 16384;

    // ---- gatherA: halo rows 0..21 -> sin_ (22x36x4 bf16, zero-padded)
    for (int idx = tid; idx < 792; idx += 256) {
        int r = idx / 36, c = idx - r * 36;
        int gy = oy - 10 + r, gx = ox - 10 + c;
        float v0 = 0.f, v1 = 0.f, v2 = 0.f, v3 = 0.f;
        if ((unsigned)gy < 128u && (unsigned)gx < 128u) {
            int off = gy * 128 + gx;
            v0 = cnn[nb + (long long)ch0 * 16384 + off];
            v1 = cnn[nb + (long long)ch1 * 16384 + off];
            v2 = cnn[nb + (long long)ch2 * 16384 + off];
            v3 = cnn[nb + (long long)ch3 * 16384 + off];
        }
        uint2 v; v.x = pack2(v0, v1); v.y = pack2(v2, v3);
        *(uint2*)(sin_ + idx * 4) = v;
    }
    __syncthreads();

    conv0_slab(sin_, s0, wB, b0, 0, oy, ox, wave, lane);       // s0 rows 0..17
    __syncthreads();

    // gatherB loads (input rows 14..35) pipelined across conv1a
    float gv[4][4];
#pragma unroll
    for (int j = 0; j < 4; ++j) {
        gv[j][0] = gv[j][1] = gv[j][2] = gv[j][3] = 0.f;
        int idx = tid + 256 * j;
        if (idx < 792) {
            int r = idx / 36, c = idx - r * 36;
            int gy = oy + 4 + r, gx = ox - 10 + c;
            if ((unsigned)gy < 128u && (unsigned)gx < 128u) {
                int off = gy * 128 + gx;
                gv[j][0] = cnn[nb + (long long)ch0 * 16384 + off];
                gv[j][1] = cnn[nb + (long long)ch1 * 16384 + off];
                gv[j][2] = cnn[nb + (long long)ch2 * 16384 + off];
                gv[j][3] = cnn[nb + (long long)ch3 * 16384 + off];
            }
        }
    }
    conv1_fp8(s0, s1, wB, b1, 0, oy - 6, ox - 6, wave, lane);
#pragma unroll
    for (int j = 0; j < 4; ++j) {
        int idx = tid + 256 * j;
        if (idx < 792) {
            uint2 v; v.x = pack2(gv[j][0], gv[j][1]); v.y = pack2(gv[j][2], gv[j][3]);
            *(uint2*)(sin_ + idx * 4) = v;
        }
    }
    __syncthreads();

    conv0_slab(sin_, s0, wB, b0, 14, oy, ox, wave, lane);      // s0 rows 14..31
    __syncthreads();

    conv1_fp8(s0, s1, wB, b1, 392, oy - 6, ox - 6, wave, lane);
    __syncthreads();

    conv2_fp8<0, 5>(s1, s2, wB + 18944, b2, oy - 4, ox - 4, wave, lane);
    conv2_fp8<5, 4>(s1, s2, wB + 18944, b2, oy - 4, ox - 4, wave, lane);
    __syncthreads();

    conv_c32_fp8<24, 20, 7, true,  true,  3, 9216, 6400>(s2, s3, wB + 32256, b3, oy - 2, ox - 2, wave, lane);
    __syncthreads();

    conv_c32_fp8<20, 16, 4, false, false, 5, 6400, 4096>(s3, s4, wB + 57856, b4, oy, ox, wave, lane);
    __syncthreads();

    // ---- conv5 (1x1 32->128) bf16 + relu + conv6 (128->2)
    {
        const unsigned short* w5p = (const unsigned short*)wB;
        bf16x8 w5f[8];
#pragma unroll
        for (int nt = 0; nt < 8; ++nt)
            w5f[nt] = *(const bf16x8*)(w5p + nt * 512 + nl * 32 + quad * 8);
        const float b6q = b6[quad & 1];
#pragma unroll 1
        for (int ii = 0; ii < 4; ++ii) {
            int mt = wave + 4 * ii;                // 16 mtiles
            int lin = (mt * 16 + nl) * 16 + quad * 4096;
            bf16x8 pf = *(const bf16x8*)(s4 + lin);
            float o0 = 0.f, o1 = 0.f;
#pragma unroll
            for (int nt = 0; nt < 8; ++nt) {
                f32x4 acc = (f32x4)0.f;
                acc = __builtin_amdgcn_mfma_f32_16x16x32_bf16(w5f[nt], pf, acc, 0, 0, 0);
                float4 bb  = *(const float4*)(b5 + nt * 16 + quad * 4);
                float4 wa  = *(const float4*)(w6 + nt * 16 + quad * 4);
                float4 wb2 = *(const float4*)(w6 + 128 + nt * 16 + quad * 4);
                float h0 = fmaxf(acc[0] + bb.x, 0.f), h1 = fmaxf(acc[1] + bb.y, 0.f);
                float h2 = fmaxf(acc[2] + bb.z, 0.f), h3 = fmaxf(acc[3] + bb.w, 0.f);
                o0 = fmaf(h0, wa.x, fmaf(h1, wa.y, fmaf(h2, wa.z, fmaf(h3, wa.w, o0))));
                o1 = fmaf(h0, wb2.x, fmaf(h1, wb2.y, fmaf(h2, wb2.z, fmaf(h3, wb2.w, o1))));
            }
            o0 += __shfl_xor(o0, 16, 64); o0 += __shfl_xor(o0, 32, 64);
            o1 += __shfl_xor(o1, 16, 64); o1 += __shfl_xor(o1, 32, 64);
            if (quad < 2) {
                float val = ((quad == 0) ? o0 : o1) + b6q;
                long long ob = (((long long)n * 38 + 2 * g + quad) * 128 + (oy + mt)) * 128 + (ox + nl);
                out[ob] = val;
            }
        }
    }
}

extern "C" void kernel_launch(void* const* d_in, const int* in_sizes, int n_in,
                              void* d_out, int out_size, void* d_ws, size_t ws_size,
                              hipStream_t stream) {
    const float* cnn = (const float*)d_in[0];
    const float* w0 = (const float*)d_in[2];  const float* b0 = (const float*)d_in[3];
    const float* w1 = (const float*)d_in[4];  const float* b1 = (const float*)d_in[5];
    const float* w2 = (const float*)d_in[6];  const float* b2 = (const float*)d_in[7];
    const float* w3 = (const float*)d_in[8];  const float* b3 = (const float*)d_in[9];
    const float* w4 = (const float*)d_in[10]; const float* b4 = (const float*)d_in[11];
    const float* w5 = (const float*)d_in[12]; const float* b5 = (const float*)d_in[13];
    const float* w6 = (const float*)d_in[14]; const float* b6 = (const float*)d_in[15];
    float* out = (float*)d_out;
    unsigned char* wB = (unsigned char*)d_ws;   // 83456 B used

    hipLaunchKernelGGL(reorder_weights, dim3(278), dim3(256), 0, stream,
                       w0, w1, w2, w3, w4, w5, wB);
    hipLaunchKernelGGL(gnn_paf_mfma, dim3(64, 304), dim3(256), 0, stream,
                       cnn, wB, b0, b1, b2, b3, b4, b5, w6, b6, out);
}

// Round 2
// 1169.848 us; speedup vs baseline: 2.0895x; 2.0895x over previous
//
#include <hip/hip_runtime.h>
#include <hip/hip_bf16.h>

typedef __bf16  bf16x8 __attribute__((ext_vector_type(8)));
typedef float   f32x4  __attribute__((ext_vector_type(4)));
typedef int     i32x4  __attribute__((ext_vector_type(4)));
typedef int     i32x8  __attribute__((ext_vector_type(8)));

__device__ __constant__ int EDGE_A[19] = {1,8,9,1,11,12,1,2,3,2,1,5,6,5,0,0,0,14,15};
__device__ __constant__ int EDGE_B[19] = {8,9,10,11,12,13,2,3,4,16,5,6,7,17,1,14,15,16,17};

#define SACT  64.0f            // activation & weight quant scale
#define SINV  (1.0f / 4096.0f) // 1/(Sw*Sa)
#define SREQ  0.015625f        // SINV*SACT = 1/64 (requant multiplier)
#define SCL1  0x7F7F7F7F       // e8m0 scale = 1.0 in every byte (opsel-proof)

__device__ __forceinline__ unsigned short f2bf(float f) {
    unsigned int x = __float_as_uint(f);
    x += 0x7FFFu + ((x >> 16) & 1u);
    return (unsigned short)(x >> 16);
}
__device__ __forceinline__ unsigned int pack2(float a, float b) {
    __hip_bfloat162 t = __float22bfloat162_rn(make_float2(a, b));
    unsigned int r; __builtin_memcpy(&r, &t, 4); return r;
}
__device__ __forceinline__ unsigned char f2fp8(float v) {
    int r = __builtin_amdgcn_cvt_pk_fp8_f32(v, 0.f, 0, false);
    return (unsigned char)(r & 0xff);
}
__device__ __forceinline__ unsigned int pk4fp8(float a, float b, float c, float d) {
    int v = __builtin_amdgcn_cvt_pk_fp8_f32(a, b, 0, false);
    v = __builtin_amdgcn_cvt_pk_fp8_f32(c, d, v, true);
    return (unsigned int)v;
}
// quantized epilogue: relu(acc*s + bias_prescaled) -> fp8x4
__device__ __forceinline__ unsigned int quant4(f32x4 a, float4 b, float s, bool oob) {
    float v0 = fmaxf(fmaf(a[0], s, b.x), 0.f);
    float v1 = fmaxf(fmaf(a[1], s, b.y), 0.f);
    float v2 = fmaxf(fmaf(a[2], s, b.z), 0.f);
    float v3 = fmaxf(fmaf(a[3], s, b.w), 0.f);
    unsigned int v = pk4fp8(v0, v1, v2, v3);
    return oob ? 0u : v;
}

// swizzles (granule-preserving XOR) -- kept for s0/s1/s4 (proven layouts)
__device__ __forceinline__ int sw8 (int l) { return l ^ ((l >> 4) & 8);  }  // 16B rows
__device__ __forceinline__ int sw48(int l) { return l ^ ((l >> 3) & 48); }  // 64B rows

__device__ __forceinline__ void store_relu4(unsigned char* dst, f32x4 a, float4 b, bool oob) {
    unsigned int lo = pack2(fmaxf(a[0] + b.x, 0.f), fmaxf(a[1] + b.y, 0.f));
    unsigned int hi = pack2(fmaxf(a[2] + b.z, 0.f), fmaxf(a[3] + b.w, 0.f));
    uint2 v; v.x = oob ? 0u : lo; v.y = oob ? 0u : hi;
    *(uint2*)dst = v;
}

// ---------------------------------------------------------------------------
// Weight pre-pass, ws BYTE layout:
//   W5 bf16 @0     : 8nt x 16 x 32 shorts                 ( 8192 B)
//   W0 bf16 @8192  : 4c x 16 x 32 shorts                  ( 4096 B)
//   W1 fp8  @12288 : 13tp x 16n x 32k, x64                ( 6656 B)
//   W2 fp8  @18944 : 13tp x 2nt x 16 x 32, x64            (13312 B)
//   W3 fp8  @32256 : 7tg x 2nt x 16n x 4q x 32ic (x128)   (28672 B)
//   W4 fp8  @60928 : 7tg x 2nt x 16n x 4q x 32ic (x128)   (28672 B)
// total 89600 B
// ---------------------------------------------------------------------------
extern "C" __global__ void __launch_bounds__(256)
reorder_weights(const float* __restrict__ w0, const float* __restrict__ w1,
                const float* __restrict__ w2, const float* __restrict__ w3,
                const float* __restrict__ w4, const float* __restrict__ w5,
                unsigned char* __restrict__ ws)
{
    int idx = blockIdx.x * 256 + threadIdx.x;
    unsigned short* wsS = (unsigned short*)ws;
    if (idx < 4096) {                       // W5 bf16
        int k = idx & 31, oc = idx >> 5;
        wsS[idx] = f2bf(w5[oc * 32 + k]);
    } else if (idx < 6144) {                // W0 bf16
        int j = idx - 4096;
        int k = j & 31, n = (j >> 5) & 15, c = j >> 9;
        int t = c * 8 + (k >> 2), ic = k & 3;
        float v = (t < 25) ? w0[(n * 4 + ic) * 25 + t] : 0.f;
        wsS[idx] = f2bf(v);
    }
    if (idx < 6656) {                       // W1 fp8
        int k = idx & 31, n = (idx >> 5) & 15, tp = idx >> 9;
        int t = 2 * tp + (k >> 4), ic = k & 15;
        float v = (t < 25) ? w1[(n * 16 + ic) * 25 + t] * SACT : 0.f;
        ws[12288 + idx] = f2fp8(v);
    } else if (idx < 19968) {               // W2 fp8
        int j = idx - 6656;
        int k = j & 31, n = (j >> 5) & 15, nt = (j >> 9) & 1, tp = j >> 10;
        int t = 2 * tp + (k >> 4), ic = k & 15, oc = nt * 16 + n;
        float v = (t < 25) ? w2[(oc * 16 + ic) * 25 + t] * SACT : 0.f;
        ws[18944 + j] = f2fp8(v);
    } else if (idx < 48640) {               // W3 fp8 (x128: tap-group layout)
        int j = idx - 19968;
        int tg = j >> 12, r = j & 4095;
        int nt = r >> 11, n = (r >> 7) & 15, q = (r >> 5) & 3, ic = r & 31;
        int tap = 4 * tg + q;
        float v = (tap < 25) ? w3[((nt * 16 + n) * 32 + ic) * 25 + tap] * SACT : 0.f;
        ws[32256 + j] = f2fp8(v);
    } else if (idx < 77312) {               // W4 fp8 (x128: tap-group layout)
        int j = idx - 48640;
        int tg = j >> 12, r = j & 4095;
        int nt = r >> 11, n = (r >> 7) & 15, q = (r >> 5) & 3, ic = r & 31;
        int tap = 4 * tg + q;
        float v = (tap < 25) ? w4[((nt * 16 + n) * 32 + ic) * 25 + tap] * SACT : 0.f;
        ws[60928 + j] = f2fp8(v);
    }
}

// ---------------------------------------------------------------------------
// conv0 (4->16) bf16 MFMA on an 18-row slab; OUTPUT fp8 x64 -> s0 16B rows.
// Tap byte-offsets hoisted out of the i-loop (depend only on quad).
// ---------------------------------------------------------------------------
__device__ __forceinline__ void conv0_slab(
    const unsigned short* __restrict__ s_in, unsigned char* __restrict__ s0,
    const unsigned char* __restrict__ wB, const float* __restrict__ b0,
    int yoff, int oy, int ox, int wave, int lane)
{
    const int nl = lane & 15, quad = lane >> 4;
    const unsigned short* w0p = (const unsigned short*)(wB + 8192);
    bf16x8 wf[4];
#pragma unroll
    for (int c = 0; c < 4; ++c)
        wf[c] = *(const bf16x8*)(w0p + c * 512 + nl * 32 + quad * 8);
    float4 bb = *(const float4*)(b0 + quad * 4);
    float4 bbs = make_float4(bb.x * SACT, bb.y * SACT, bb.z * SACT, bb.w * SACT);

    int coff0[4], coff1[4];
#pragma unroll
    for (int c = 0; c < 4; ++c) {
        int t0 = c * 8 + quad * 2, t1 = t0 + 1;
        if (t0 > 24) t0 = 24;
        if (t1 > 24) t1 = 24;
        coff0[c] = ((t0 / 5) * 36 + (t0 % 5)) * 8;
        coff1[c] = ((t1 / 5) * 36 + (t1 % 5)) * 8;
    }
    const unsigned char* sB = (const unsigned char*)s_in;

#pragma unroll 1
    for (int i = 0; i < 9; ++i) {
        int mt = wave + 4 * i;                 // 36 mtiles = 576 px (18r x 32)
        int p = mt * 16 + nl;
        int y = p >> 5, x = p & 31;
        int abase = (y * 36 + x) * 8;
        f32x4 acc = (f32x4)0.f;
#pragma unroll
        for (int c = 0; c < 4; ++c) {
            uint2 lo = *(const uint2*)(sB + abase + coff0[c]);
            uint2 hi = *(const uint2*)(sB + abase + coff1[c]);
            bf16x8 a;
            ((uint2*)&a)[0] = lo; ((uint2*)&a)[1] = hi;
            acc = __builtin_amdgcn_mfma_f32_16x16x32_bf16(wf[c], a, acc, 0, 0, 0);
        }
        bool oob = ((unsigned)(oy - 8 + y + yoff) >= 128u) || ((unsigned)(ox - 8 + x) >= 128u);
        *(unsigned int*)(s0 + sw8(p * 16 + quad * 4)) = quant4(acc, bbs, SACT, oob);
    }
}

// ---------------------------------------------------------------------------
// conv1 half-slab, FP8: in s0 (18r x 32, 16B rows), out s1 fp8 16B rows.
// Paired-tap (K=32 = 2 taps x 16ch), chunked (5) to bound registers.
// ---------------------------------------------------------------------------
__device__ __forceinline__ void conv1_fp8(
    const unsigned char* __restrict__ s0, unsigned char* __restrict__ s1,
    const unsigned char* __restrict__ wB, const float* __restrict__ b1,
    int POFF, int gy0, int gx0, int wave, int lane)
{
    const int nl = lane & 15, quad = lane >> 4;
    const int h = quad >> 1, g8 = (quad & 1) * 8;

    int abase[7];
#pragma unroll
    for (int i = 0; i < 7; ++i) {
        int p = (wave + 4 * i) * 16 + nl;
        if (p > 391) p = 391;
        int y = p / 28, x = p - y * 28;
        abase[i] = (y * 32 + x) * 16 + g8;
    }
    f32x4 acc[7];
#pragma unroll
    for (int i = 0; i < 7; ++i) acc[i] = (f32x4)0.f;

    const unsigned char* wp = wB + 12288 + nl * 32 + quad * 8;

#pragma unroll 1
    for (int c0 = 0; c0 < 13; c0 += 5) {
        long wl[5];
#pragma unroll
        for (int tp = 0; tp < 5; ++tp)
            if (c0 + tp < 13) wl[tp] = *(const long*)(wp + (c0 + tp) * 512);
#pragma unroll
        for (int tp = 0; tp < 5; ++tp) {
            if (c0 + tp < 13) {
                int t = 2 * (c0 + tp) + h;
                if (t > 24) t = 24;            // padded half; weights zero
                int dy = t / 5, dx = t - 5 * dy;
                int toff = (dy * 32 + dx) * 16;
#pragma unroll
                for (int i = 0; i < 7; ++i)
                    if (wave + 4 * i < 25) {
                        long a = *(const long*)(s0 + sw8(abase[i] + toff));
                        acc[i] = __builtin_amdgcn_mfma_f32_16x16x32_fp8_fp8(wl[tp], a, acc[i], 0, 0, 0);
                    }
            }
        }
    }

    float4 bb = *(const float4*)(b1 + quad * 4);
    float4 bbs = make_float4(bb.x * SACT, bb.y * SACT, bb.z * SACT, bb.w * SACT);
#pragma unroll
    for (int i = 0; i < 7; ++i) {
        int p = (wave + 4 * i) * 16 + nl;
        if (p < 392) {
            int pg = p + POFF;
            int y = pg / 28, x = pg - y * 28;
            bool oob = ((unsigned)(gy0 + y) >= 128u) || ((unsigned)(gx0 + x) >= 128u);
            *(unsigned int*)(s1 + sw8(pg * 16 + quad * 4)) = quant4(acc[i], bbs, SREQ, oob);
        }
    }
}

// ---------------------------------------------------------------------------
// conv2: fp8 paired-tap (CIN=16), NT=2, two m-passes (I0/NI) to bound regs.
// in s1 [784][16B] sw8, out s2 [576 px][48B stride, ch0..31 @ +0..31].
// ---------------------------------------------------------------------------
template<int I0, int NI>
__device__ __forceinline__ void conv2_fp8(
    const unsigned char* __restrict__ s1, unsigned char* __restrict__ s2,
    const unsigned char* __restrict__ wA, const float* __restrict__ b2,
    int gy0, int gx0, int wave, int lane)
{
    const int nl = lane & 15, quad = lane >> 4;
    const int h = quad >> 1, g8 = (quad & 1) * 8;

    int abase[NI];
#pragma unroll
    for (int i = 0; i < NI; ++i) {
        int p = (wave + 4 * (I0 + i)) * 16 + nl;
        int y = p / 24, x = p - y * 24;
        abase[i] = (y * 28 + x) * 16 + g8;
    }
    f32x4 acc[NI][2];
#pragma unroll
    for (int i = 0; i < NI; ++i) { acc[i][0] = (f32x4)0.f; acc[i][1] = (f32x4)0.f; }

    const unsigned char* wp = wA + nl * 32 + quad * 8;

#pragma unroll 1
    for (int c0 = 0; c0 < 13; c0 += 3) {
        long wl[3][2];
#pragma unroll
        for (int tp = 0; tp < 3; ++tp)
            if (c0 + tp < 13) {
                wl[tp][0] = *(const long*)(wp + ((c0 + tp) * 2 + 0) * 512);
                wl[tp][1] = *(const long*)(wp + ((c0 + tp) * 2 + 1) * 512);
            }
#pragma unroll
        for (int tp = 0; tp < 3; ++tp) {
            if (c0 + tp < 13) {
                int t = 2 * (c0 + tp) + h;
                if (t > 24) t = 24;
                int dy = t / 5, dx = t - 5 * dy;
                int toff = (dy * 28 + dx) * 16;
#pragma unroll
                for (int i = 0; i < NI; ++i) {
                    long a = *(const long*)(s1 + sw8(abase[i] + toff));
                    acc[i][0] = __builtin_amdgcn_mfma_f32_16x16x32_fp8_fp8(wl[tp][0], a, acc[i][0], 0, 0, 0);
                    acc[i][1] = __builtin_amdgcn_mfma_f32_16x16x32_fp8_fp8(wl[tp][1], a, acc[i][1], 0, 0, 0);
                }
            }
        }
    }

#pragma unroll
    for (int i = 0; i < NI; ++i) {
        int p = (wave + 4 * (I0 + i)) * 16 + nl;
        int y = p / 24, x = p - y * 24;
        bool oob = ((unsigned)(gy0 + y) >= 128u) || ((unsigned)(gx0 + x) >= 128u);
#pragma unroll
        for (int nt = 0; nt < 2; ++nt) {
            float4 bb = *(const float4*)(b2 + nt * 16 + quad * 4);
            float4 bbs = make_float4(bb.x * SACT, bb.y * SACT, bb.z * SACT, bb.w * SACT);
            *(unsigned int*)(s2 + p * 48 + nt * 16 + quad * 4) =
                quant4(acc[i][nt], bbs, SREQ, oob);
        }
    }
}

// ---------------------------------------------------------------------------
// conv3/conv4: MX-scaled fp8 MFMA, K=128 = 4 taps x 32ic (scales = 1.0).
// A operand: per lane 32 CONTIGUOUS bytes = pixel's tap(4tg+quad) channels.
// in: [px][48B stride] (16B-aligned, stride-12-banks => uniform 2-way, free).
// FP8OUT: fp8 to 48B-stride planes; else bf16 to 64B rows (sw48).
// ---------------------------------------------------------------------------
template<int SINW, int SOUT, int MAXM, bool GUARD, bool FP8OUT>
__device__ __forceinline__ void conv_c32_mx(
    const unsigned char* __restrict__ sinB, unsigned char* __restrict__ soutB,
    const unsigned char* __restrict__ wA, const float* __restrict__ bias,
    int gy0, int gx0, int wave, int lane)
{
    constexpr int NM = (SOUT * SOUT) / 16;
    const int nl = lane & 15, quad = lane >> 4;

    int abase[MAXM];
#pragma unroll
    for (int i = 0; i < MAXM; ++i) {
        int p = (wave + 4 * i) * 16 + nl;
        if (GUARD && p > SOUT * SOUT - 1) p = SOUT * SOUT - 1;
        int y = p / SOUT, x = p - y * SOUT;
        abase[i] = (y * SINW + x) * 48;
    }
    f32x4 acc[MAXM][2];
#pragma unroll
    for (int i = 0; i < MAXM; ++i) { acc[i][0] = (f32x4)0.f; acc[i][1] = (f32x4)0.f; }

    const unsigned char* wp = wA + nl * 128 + quad * 32;

#pragma unroll 1
    for (int tg = 0; tg < 7; ++tg) {
        int t = 4 * tg + quad;
        if (t > 24) t = 24;                    // padded taps; weights zero
        int dy = t / 5, dx = t - 5 * dy;
        int to = (dy * SINW + dx) * 48;
        i32x8 wl0 = *(const i32x8*)(wp + tg * 4096);
        i32x8 wl1 = *(const i32x8*)(wp + tg * 4096 + 2048);
#pragma unroll
        for (int i = 0; i < MAXM; ++i)
            if (!GUARD || wave + 4 * i < NM) {
                i32x4 alo = *(const i32x4*)(sinB + abase[i] + to);
                i32x4 ahi = *(const i32x4*)(sinB + abase[i] + to + 16);
                i32x8 a;
                ((i32x4*)&a)[0] = alo; ((i32x4*)&a)[1] = ahi;
                acc[i][0] = __builtin_amdgcn_mfma_scale_f32_16x16x128_f8f6f4(
                                wl0, a, acc[i][0], 0, 0, 0, SCL1, 0, SCL1);
                acc[i][1] = __builtin_amdgcn_mfma_scale_f32_16x16x128_f8f6f4(
                                wl1, a, acc[i][1], 0, 0, 0, SCL1, 0, SCL1);
            }
    }

#pragma unroll
    for (int i = 0; i < MAXM; ++i) {
        int p = (wave + 4 * i) * 16 + nl;
        if (!GUARD || p < SOUT * SOUT) {
            int y = p / SOUT, x = p - y * SOUT;
            bool oob = ((unsigned)(gy0 + y) >= 128u) || ((unsigned)(gx0 + x) >= 128u);
#pragma unroll
            for (int nt = 0; nt < 2; ++nt) {
                float4 bb = *(const float4*)(bias + nt * 16 + quad * 4);
                if (FP8OUT) {
                    float4 bbs = make_float4(bb.x * SACT, bb.y * SACT, bb.z * SACT, bb.w * SACT);
                    *(unsigned int*)(soutB + p * 48 + nt * 16 + quad * 4) =
                        quant4(acc[i][nt], bbs, SREQ, oob);
                } else {
                    f32x4 s;
                    s[0] = acc[i][nt][0] * SINV; s[1] = acc[i][nt][1] * SINV;
                    s[2] = acc[i][nt][2] * SINV; s[3] = acc[i][nt][3] * SINV;
                    store_relu4(soutB + sw48(p * 64 + nt * 32 + quad * 8), s, bb, oob);
                }
            }
        }
    }
}

// ---------------------------------------------------------------------------
// Fused pipeline: 256 threads = one 16x16 output tile. LDS 46848 B:
//   s1 @0 12544 | s3 @0 19200 | sin @12544 6336 | s0 @19200 9216
//   s2 @19200 27648 | s4 @19200 16384   (ping-pong, liveness-checked)
// ---------------------------------------------------------------------------
extern "C" __global__ void __launch_bounds__(256, 3)
gnn_paf_mfma(const float* __restrict__ cnn, const unsigned char* __restrict__ wB,
             const float* __restrict__ b0, const float* __restrict__ b1,
             const float* __restrict__ b2, const float* __restrict__ b3,
             const float* __restrict__ b4, const float* __restrict__ b5,
             const float* __restrict__ w6, const float* __restrict__ b6,
             float* __restrict__ out)
{
    __shared__ __align__(64) unsigned char smem[46848];
    unsigned char*  const s1   = smem;                             // 12544
    unsigned char*  const s3   = smem;                             // 19200 (conv3 out)
    unsigned short* const sin_ = (unsigned short*)(smem + 12544);  // 6336
    unsigned char*  const s0   = smem + 19200;                     // 9216
    unsigned char*  const s2   = smem + 19200;                     // 27648
    unsigned char*  const s4   = smem + 19200;                     // 16384

    const int tid  = threadIdx.x;
    const int lane = tid & 63, wave = tid >> 6;       // 4 waves
    const int tile = blockIdx.x, img = blockIdx.y;
    const int oy = (tile >> 3) * 16, ox = (tile & 7) * 16;
    const int n = img / 19, g = img - n * 19;
    const int ch0 = EDGE_A[g], ch1 = EDGE_B[g], ch2 = 19 + 2 * g, ch3 = 20 + 2 * g;
    const int nl = lane & 15, quad = lane >> 4;
    const long long nb = (long long)n * 57 * 16384;

    // ---- gatherA: halo rows 0..21 -> sin_ (22x36x4 bf16, zero-padded)
    for (int idx = tid; idx < 792; idx += 256) {
        int r = idx / 36, c = idx - r * 36;
        int gy = oy - 10 + r, gx = ox - 10 + c;
        float v0 = 0.f, v1 = 0.f, v2 = 0.f, v3 = 0.f;
        if ((unsigned)gy < 128u && (unsigned)gx < 128u) {
            int off = gy * 128 + gx;
            v0 = cnn[nb + (long long)ch0 * 16384 + off];
            v1 = cnn[nb + (long long)ch1 * 16384 + off];
            v2 = cnn[nb + (long long)ch2 * 16384 + off];
            v3 = cnn[nb + (long long)ch3 * 16384 + off];
        }
        uint2 v; v.x = pack2(v0, v1); v.y = pack2(v2, v3);
        *(uint2*)(sin_ + idx * 4) = v;
    }
    __syncthreads();

    conv0_slab(sin_, s0, wB, b0, 0, oy, ox, wave, lane);       // s0 rows 0..17
    __syncthreads();

    // gatherB loads (input rows 14..35) pipelined across conv1a
    float gv[4][4];
#pragma unroll
    for (int j = 0; j < 4; ++j) {
        gv[j][0] = gv[j][1] = gv[j][2] = gv[j][3] = 0.f;
        int idx = tid + 256 * j;
        if (idx < 792) {
            int r = idx / 36, c = idx - r * 36;
            int gy = oy + 4 + r, gx = ox - 10 + c;
            if ((unsigned)gy < 128u && (unsigned)gx < 128u) {
                int off = gy * 128 + gx;
                gv[j][0] = cnn[nb + (long long)ch0 * 16384 + off];
                gv[j][1] = cnn[nb + (long long)ch1 * 16384 + off];
                gv[j][2] = cnn[nb + (long long)ch2 * 16384 + off];
                gv[j][3] = cnn[nb + (long long)ch3 * 16384 + off];
            }
        }
    }
    conv1_fp8(s0, s1, wB, b1, 0, oy - 6, ox - 6, wave, lane);
#pragma unroll
    for (int j = 0; j < 4; ++j) {
        int idx = tid + 256 * j;
        if (idx < 792) {
            uint2 v; v.x = pack2(gv[j][0], gv[j][1]); v.y = pack2(gv[j][2], gv[j][3]);
            *(uint2*)(sin_ + idx * 4) = v;
        }
    }
    __syncthreads();

    conv0_slab(sin_, s0, wB, b0, 14, oy, ox, wave, lane);      // s0 rows 14..31
    __syncthreads();

    conv1_fp8(s0, s1, wB, b1, 392, oy - 6, ox - 6, wave, lane);
    __syncthreads();

    conv2_fp8<0, 5>(s1, s2, wB + 18944, b2, oy - 4, ox - 4, wave, lane);
    conv2_fp8<5, 4>(s1, s2, wB + 18944, b2, oy - 4, ox - 4, wave, lane);
    __syncthreads();

    conv_c32_mx<24, 20, 7, true,  true >(s2, s3, wB + 32256, b3, oy - 2, ox - 2, wave, lane);
    __syncthreads();

    conv_c32_mx<20, 16, 4, false, false>(s3, s4, wB + 60928, b4, oy, ox, wave, lane);
    __syncthreads();

    // ---- conv5 (1x1 32->128) bf16 + relu + conv6 (128->2)
    {
        const unsigned short* w5p = (const unsigned short*)wB;
        bf16x8 w5f[8];
#pragma unroll
        for (int nt = 0; nt < 8; ++nt)
            w5f[nt] = *(const bf16x8*)(w5p + nt * 512 + nl * 32 + quad * 8);
        const float b6q = b6[quad & 1];
#pragma unroll 1
        for (int ii = 0; ii < 4; ++ii) {
            int mt = wave + 4 * ii;                // 16 mtiles
            int lin = (mt * 16 + nl) * 64 + quad * 16;
            bf16x8 pf = *(const bf16x8*)(s4 + sw48(lin));
            float o0 = 0.f, o1 = 0.f;
#pragma unroll
            for (int nt = 0; nt < 8; ++nt) {
                f32x4 acc = (f32x4)0.f;
                acc = __builtin_amdgcn_mfma_f32_16x16x32_bf16(w5f[nt], pf, acc, 0, 0, 0);
                float4 bb  = *(const float4*)(b5 + nt * 16 + quad * 4);
                float4 wa  = *(const float4*)(w6 + nt * 16 + quad * 4);
                float4 wb2 = *(const float4*)(w6 + 128 + nt * 16 + quad * 4);
                float h0 = fmaxf(acc[0] + bb.x, 0.f), h1 = fmaxf(acc[1] + bb.y, 0.f);
                float h2 = fmaxf(acc[2] + bb.z, 0.f), h3 = fmaxf(acc[3] + bb.w, 0.f);
                o0 = fmaf(h0, wa.x, fmaf(h1, wa.y, fmaf(h2, wa.z, fmaf(h3, wa.w, o0))));
                o1 = fmaf(h0, wb2.x, fmaf(h1, wb2.y, fmaf(h2, wb2.z, fmaf(h3, wb2.w, o1))));
            }
            o0 += __shfl_xor(o0, 16, 64); o0 += __shfl_xor(o0, 32, 64);
            o1 += __shfl_xor(o1, 16, 64); o1 += __shfl_xor(o1, 32, 64);
            if (quad < 2) {
                float val = ((quad == 0) ? o0 : o1) + b6q;
                long long ob = (((long long)n * 38 + 2 * g + quad) * 128 + (oy + mt)) * 128 + (ox + nl);
                out[ob] = val;
            }
        }
    }
}

extern "C" void kernel_launch(void* const* d_in, const int* in_sizes, int n_in,
                              void* d_out, int out_size, void* d_ws, size_t ws_size,
                              hipStream_t stream) {
    const float* cnn = (const float*)d_in[0];
    const float* w0 = (const float*)d_in[2];  const float* b0 = (const float*)d_in[3];
    const float* w1 = (const float*)d_in[4];  const float* b1 = (const float*)d_in[5];
    const float* w2 = (const float*)d_in[6];  const float* b2 = (const float*)d_in[7];
    const float* w3 = (const float*)d_in[8];  const float* b3 = (const float*)d_in[9];
    const float* w4 = (const float*)d_in[10]; const float* b4 = (const float*)d_in[11];
    const float* w5 = (const float*)d_in[12]; const float* b5 = (const float*)d_in[13];
    const float* w6 = (const float*)d_in[14]; const float* b6 = (const float*)d_in[15];
    float* out = (float*)d_out;
    unsigned char* wB = (unsigned char*)d_ws;   // 89600 B used

    hipLaunchKernelGGL(reorder_weights, dim3(302), dim3(256), 0, stream,
                       w0, w1, w2, w3, w4, w5, wB);
    hipLaunchKernelGGL(gnn_paf_mfma, dim3(64, 304), dim3(256), 0, stream,
                       cnn, wB, b0, b1, b2, b3, b4, b5, w6, b6, out);
}